// Round 6
// baseline (8444.274 us; speedup 1.0000x reference)
//
#include <hip/hip_runtime.h>

// LSTM (B=512, T=1024, I=64, H=128) + FC(128->256->1).
// v7: distributed MFMA recurrence on ALL 256 CUs.
// v6 post-mortem: N=16 (batch rows/MFMA tile) forced 32 blocks -> 224 CUs
// idle and 2300 cy/step of MFMA on each active CU (52% per-CU MfmaUtil).
// v7 splits the gate dimension too: 256 blocks = 32 batch-groups x 8
// unit-blocks. Block (g,u) = 1 wave (64 thr) owns units 16u..16u+15 (all 4
// classes) x 16 rows: 72 MFMA/step (24 x-part + 48 h-part, bf16x3).
// Blocks exchange h each step via a 516KB global buffer (L2-resident,
// laid out in exact MFMA-B-frag order) with monotonic flags:
//   write h-split -> release fence -> flag = t+1 ; peers spin (relaxed
//   polls + s_sleep), acquire fence, load. Deadlock-free: single monotonic
//   condition; overwrite of h(t-2) is safe because observing a peer's flag
//   = t implies that peer finished reading h(t-2).
// blockIdx swizzle puts a group's 8 blocks on ONE XCD (blockIdx%8 ==
// g%8) so the exchange stays in one L2 (correctness is scope-"agent",
// placement only affects latency). x-part MFMAs + x prefetch/convert run
// BEFORE the spin (h-independent) to fill the wait. No LDS. Update is
// lane-local via the v6-validated C layout (row n = lane&15, units
// 16u + 4*(lane>>4) + reg). Splits: W = rn/rn (init), x/h = trunc/rn-ish
// trunc (err budget ~4x v6's 7.6e-6 absmax).

#define T_STEPS 1024
#define ISZ 64
#define HSZ 128
#define ROWS 16
#define NGROUP 32
#define NUBLK 8

typedef __attribute__((ext_vector_type(8))) short bf16x8;
typedef __attribute__((ext_vector_type(4))) float f32x4;
typedef __attribute__((ext_vector_type(4))) unsigned u32x4;
typedef __attribute__((ext_vector_type(2))) unsigned u32x2;

#define MFMA __builtin_amdgcn_mfma_f32_16x16x32_bf16

static __device__ __forceinline__ unsigned short bf16_rn(float f) {
    unsigned u = __float_as_uint(f);
    return (unsigned short)((u + 0x7FFFu + ((u >> 16) & 1u)) >> 16);
}
static __device__ __forceinline__ float bf16_f(unsigned short h) {
    return __uint_as_float(((unsigned)h) << 16);
}
static __device__ __forceinline__ float bfhi(float f) {  // truncate to bf16
    return __uint_as_float(__float_as_uint(f) & 0xFFFF0000u);
}
// dword = [top16(f0) | top16(f1)<<16]  (one v_perm_b32)
static __device__ __forceinline__ unsigned pack_hi(float f0, float f1) {
    return __builtin_amdgcn_perm(__float_as_uint(f1), __float_as_uint(f0), 0x07060302u);
}
static __device__ __forceinline__ float sigm(float s) {
    return __builtin_amdgcn_rcpf(1.0f + __expf(-s));
}
static __device__ __forceinline__ float tanh_(float s) {
    return fmaf(-2.0f, __builtin_amdgcn_rcpf(__expf(2.0f * s) + 1.0f), 1.0f);
}
// split 8 fp32 -> bf16 hi (trunc) + bf16 lo (trunc of residual); exact-sub residual
static __device__ __forceinline__ void split8(const float4& a, const float4& b,
                                              bf16x8& H, bf16x8& L) {
    u32x4 th = { pack_hi(a.x, a.y), pack_hi(a.z, a.w),
                 pack_hi(b.x, b.y), pack_hi(b.z, b.w) };
    float r0 = a.x - bfhi(a.x), r1 = a.y - bfhi(a.y);
    float r2 = a.z - bfhi(a.z), r3 = a.w - bfhi(a.w);
    float r4 = b.x - bfhi(b.x), r5 = b.y - bfhi(b.y);
    float r6 = b.z - bfhi(b.z), r7 = b.w - bfhi(b.w);
    u32x4 tl = { pack_hi(r0, r1), pack_hi(r2, r3),
                 pack_hi(r4, r5), pack_hi(r6, r7) };
    H = __builtin_bit_cast(bf16x8, th);
    L = __builtin_bit_cast(bf16x8, tl);
}

__global__ void zero_ws_kernel(unsigned* __restrict__ p, int n) {
    int i = blockIdx.x * 256 + threadIdx.x;
    if (i < n) p[i] = 0;
}

__global__ __launch_bounds__(64, 1)
void lstm_persist(const float* __restrict__ x,
                  const float* __restrict__ W_ih,
                  const float* __restrict__ W_hh,
                  const float* __restrict__ b_ih,
                  const float* __restrict__ b_hh,
                  const float* __restrict__ W1,
                  const float* __restrict__ b1,
                  const float* __restrict__ W2,
                  const float* __restrict__ b2,
                  float* __restrict__ out,
                  int* __restrict__ flags,              // [g][parity][u]  (32*2*8)
                  unsigned short* __restrict__ exH,     // [g*2+p][row][128 units]
                  unsigned short* __restrict__ exL)
{
    const int blk = blockIdx.x;
    // swizzle: all 8 unit-blocks of group g share blockIdx%8 -> same XCD
    const int g = (blk & 7) | (((blk >> 6) & 3) << 3);
    const int u = (blk >> 3) & 7;
    const int lane = threadIdx.x;
    const int n = lane & 15;       // batch row in group (A m-row, B/C n-col)
    const int qrt = lane >> 4;     // 0..3
    const int b0 = g * ROWS;

    // ---- A-fragments: gate rows {cls*128 + 16u + n}, rn/rn split (one-time) ----
    bf16x8 Ah[4][6], Al[4][6];
    #pragma unroll
    for (int cls = 0; cls < 4; ++cls) {
        const int grow = cls * HSZ + 16 * u + n;
        #pragma unroll
        for (int kk = 0; kk < 6; ++kk) {
            const int cb = kk * 32 + qrt * 8;
            const float* src = (cb < ISZ) ? (W_ih + (size_t)grow * ISZ + cb)
                                          : (W_hh + (size_t)grow * HSZ + (cb - ISZ));
            #pragma unroll
            for (int e = 0; e < 8; ++e) {
                float f = src[e];
                unsigned short hi = bf16_rn(f);
                Ah[cls][kk][e] = (short)hi;
                Al[cls][kk][e] = (short)bf16_rn(f - bf16_f(hi));
            }
        }
    }
    // bias folded into accumulator init (C layout: row m = 4*qrt+r, col n)
    f32x4 biasV[4];
    #pragma unroll
    for (int cls = 0; cls < 4; ++cls)
        #pragma unroll
        for (int r = 0; r < 4; ++r) {
            const int gg = cls * HSZ + 16 * u + 4 * qrt + r;
            biasV[cls][r] = b_ih[gg] + b_hh[gg];
        }
    float cst[4] = {0.f, 0.f, 0.f, 0.f};

    // ---- x stream: lane loads x[b0+n][t][qrt*8 .. +7] and [32+qrt*8 .. +7] ----
    const float* xb = x + ((size_t)(b0 + n) * T_STEPS) * ISZ + qrt * 8;
    bf16x8 BxH[2], BxL[2];
    {
        float4 a0 = *(const float4*)(xb + 0),  a1 = *(const float4*)(xb + 4);
        float4 a2 = *(const float4*)(xb + 32), a3 = *(const float4*)(xb + 36);
        split8(a0, a1, BxH[0], BxL[0]);
        split8(a2, a3, BxH[1], BxL[1]);
    }

    const int fbase = g * 16;   // flags index base: [g][p][u] = g*16 + p*8 + u

    for (int t = 0; t < T_STEPS; ++t) {
        // -- issue x(t+1) prefetch (HBM/L3; consumed next iter) --
        float4 nx0, nx1, nx2, nx3;
        const bool pfv = (t + 1 < T_STEPS);
        if (pfv) {
            const float* xp = xb + (size_t)(t + 1) * ISZ;
            nx0 = *(const float4*)(xp + 0);  nx1 = *(const float4*)(xp + 4);
            nx2 = *(const float4*)(xp + 32); nx3 = *(const float4*)(xp + 36);
        }

        // -- x-part MFMAs (h-independent: runs before/while peers finish) --
        f32x4 C[4] = { biasV[0], biasV[1], biasV[2], biasV[3] };
        #pragma unroll
        for (int kk = 0; kk < 2; ++kk)
            #pragma unroll
            for (int cls = 0; cls < 4; ++cls) {
                C[cls] = MFMA(Ah[cls][kk], BxH[kk], C[cls], 0, 0, 0);
                C[cls] = MFMA(Ah[cls][kk], BxL[kk], C[cls], 0, 0, 0);
                C[cls] = MFMA(Al[cls][kk], BxH[kk], C[cls], 0, 0, 0);
            }

        // -- wait for h(t-1) from all 8 unit-blocks of this group --
        const int p = (t + 1) & 1;          // parity buffer holding h(t-1)
        if (t > 0) {
            const int* fl = flags + fbase + p * 8;
            bool ok;
            do {
                int v = __hip_atomic_load(fl + (lane & 7), __ATOMIC_RELAXED,
                                          __HIP_MEMORY_SCOPE_AGENT);
                ok = __all(v >= t);
                if (!ok) __builtin_amdgcn_s_sleep(1);
            } while (!ok);
            __builtin_amdgcn_fence(__ATOMIC_ACQUIRE, "agent");
        }

        // -- h-part: load B-frags straight from exchange (L2), MFMA --
        const unsigned short* hb = exH + ((size_t)(g * 2 + p) * ROWS + n) * HSZ;
        const unsigned short* lb = exL + ((size_t)(g * 2 + p) * ROWS + n) * HSZ;
        #pragma unroll
        for (int kk = 0; kk < 4; ++kk) {
            bf16x8 bh = *(const bf16x8*)(hb + kk * 32 + qrt * 8);
            bf16x8 bl = *(const bf16x8*)(lb + kk * 32 + qrt * 8);
            #pragma unroll
            for (int cls = 0; cls < 4; ++cls) {
                C[cls] = MFMA(Ah[cls][kk + 2], bh, C[cls], 0, 0, 0);
                C[cls] = MFMA(Ah[cls][kk + 2], bl, C[cls], 0, 0, 0);
                C[cls] = MFMA(Al[cls][kk + 2], bh, C[cls], 0, 0, 0);
            }
        }

        // -- convert x(t+1) while MFMAs drain --
        if (pfv) { split8(nx0, nx1, BxH[0], BxL[0]); split8(nx2, nx3, BxH[1], BxL[1]); }

        // -- lane-local c/h update: units 16u+4*qrt+r, row n --
        float hv[4];
        #pragma unroll
        for (int r = 0; r < 4; ++r) {
            float ig = sigm (C[0][r]);
            float fg = sigm (C[1][r]);
            float gv = tanh_(C[2][r]);
            float og = sigm (C[3][r]);
            cst[r] = fmaf(fg, cst[r], ig * gv);
            hv[r] = og * tanh_(cst[r]);
        }

        // -- pack h(t) (bf16 hi/lo) and publish --
        const int q = t & 1;
        unsigned dh0 = pack_hi(hv[0], hv[1]), dh1 = pack_hi(hv[2], hv[3]);
        float s0 = hv[0] - bfhi(hv[0]), s1 = hv[1] - bfhi(hv[1]);
        float s2 = hv[2] - bfhi(hv[2]), s3 = hv[3] - bfhi(hv[3]);
        unsigned dl0 = pack_hi(s0, s1), dl1 = pack_hi(s2, s3);
        unsigned short* sb = exH + ((size_t)(g * 2 + q) * ROWS + n) * HSZ + 16 * u + 4 * qrt;
        unsigned short* sl = exL + ((size_t)(g * 2 + q) * ROWS + n) * HSZ + 16 * u + 4 * qrt;
        *(u32x2*)sb = (u32x2){dh0, dh1};
        *(u32x2*)sl = (u32x2){dl0, dl1};
        __builtin_amdgcn_fence(__ATOMIC_RELEASE, "agent");
        if (lane == 0)
            __hip_atomic_store(flags + fbase + q * 8 + u, t + 1, __ATOMIC_RELAXED,
                               __HIP_MEMORY_SCOPE_AGENT);
    }

    // ---- FC head: rows 2u, 2u+1 of this group; h(1023) is in parity 1 ----
    {
        const int* fl = flags + fbase + 8;
        bool ok;
        do {
            int v = __hip_atomic_load(fl + (lane & 7), __ATOMIC_RELAXED,
                                      __HIP_MEMORY_SCOPE_AGENT);
            ok = __all(v >= T_STEPS);
            if (!ok) __builtin_amdgcn_s_sleep(1);
        } while (!ok);
        __builtin_amdgcn_fence(__ATOMIC_ACQUIRE, "agent");

        const int row = 2 * u + (lane >> 5);      // lanes 0-31: row 2u; 32-63: 2u+1
        const int l5  = lane & 31;
        const int m0  = l5 * 8;                   // 8 fc1 units per lane
        const unsigned short* hb = exH + ((size_t)(g * 2 + 1) * ROWS + row) * HSZ;
        const unsigned short* lb = exL + ((size_t)(g * 2 + 1) * ROWS + row) * HSZ;
        float acc = 0.0f;
        #pragma unroll 1
        for (int i = 0; i < 8; ++i) {
            const int m = m0 + i;
            float a = b1[m];
            const float* w1r = W1 + (size_t)m * HSZ;
            for (int k8 = 0; k8 < 16; ++k8) {
                bf16x8 hh = *(const bf16x8*)(hb + k8 * 8);
                bf16x8 ll = *(const bf16x8*)(lb + k8 * 8);
                float4 wa = *(const float4*)(w1r + k8 * 8);
                float4 wb = *(const float4*)(w1r + k8 * 8 + 4);
                #pragma unroll
                for (int e = 0; e < 8; ++e) {
                    float hvv = bf16_f((unsigned short)hh[e]) + bf16_f((unsigned short)ll[e]);
                    float w = (e < 4) ? ((e == 0) ? wa.x : (e == 1) ? wa.y : (e == 2) ? wa.z : wa.w)
                                      : ((e == 4) ? wb.x : (e == 5) ? wb.y : (e == 6) ? wb.z : wb.w);
                    a = fmaf(w, hvv, a);
                }
            }
            acc = fmaf(a, W2[m], acc);
        }
        #pragma unroll
        for (int off = 16; off >= 1; off >>= 1)
            acc += __shfl_down(acc, off, 32);
        if (l5 == 0) out[b0 + row] = acc + b2[0];
    }
}

extern "C" void kernel_launch(void* const* d_in, const int* in_sizes, int n_in,
                              void* d_out, int out_size, void* d_ws, size_t ws_size,
                              hipStream_t stream) {
    const float* x    = (const float*)d_in[0];
    const float* W_ih = (const float*)d_in[1];
    const float* W_hh = (const float*)d_in[2];
    const float* b_ih = (const float*)d_in[3];
    const float* b_hh = (const float*)d_in[4];
    const float* W1   = (const float*)d_in[5];
    const float* b1   = (const float*)d_in[6];
    const float* W2   = (const float*)d_in[7];
    const float* b2   = (const float*)d_in[8];
    float* out = (float*)d_out;

    // workspace layout: [flags 4KB][exH 256KB][exL 256KB] = 516KB (zeroed per launch)
    int* flags = (int*)d_ws;
    unsigned short* exH = (unsigned short*)((char*)d_ws + 4096);
    unsigned short* exL = exH + (size_t)NGROUP * 2 * ROWS * HSZ;   // +131072 shorts
    const int ws_dwords = (4096 + 2 * NGROUP * 2 * ROWS * HSZ * 2) / 4;  // 132096

    zero_ws_kernel<<<dim3((ws_dwords + 255) / 256), dim3(256), 0, stream>>>(
        (unsigned*)d_ws, ws_dwords);
    lstm_persist<<<dim3(256), dim3(64), 0, stream>>>(
        x, W_ih, W_hh, b_ih, b_hh, W1, b1, W2, b2, out, flags, exH, exL);
}

// Round 7
// 1418.856 us; speedup vs baseline: 5.9515x; 5.9515x over previous
//
#include <hip/hip_runtime.h>

// LSTM (B=512, T=1024, I=64, H=128) + FC(128->256->1), all fp32.
// Persistent fused kernel: 256 blocks x 512 threads (8 waves, 2/SIMD),
// BCHUNK=2 batch rows/block for the whole T loop (no grid sync ever).
//
// v8: v7's distributed attempt proved per-step cross-CU sync costs ~8 us
// (agent fences -> L2 writeback, WRITE_SIZE 270MB). Recurrence stays
// in-block. v5 calibration: VALU 2265 cy/SIMD, LDS 2304 cy/CU, step 3595 —
// per-wave overhead (fold/act/loop ~83 inst) was multiplied by 16 waves.
// v8 halves the wave count and doubles per-thread work: thread (grp, c)
// owns 2 units x 4 classes = 8 gate rows over 24-col chunk c, BOTH rows:
// 384 FMA + 12 ds_read_b128/thread -> per CU LDS 96 reads (1150 cy, half
// of v5), per SIMD VALU ~2100 cy (overhead amortized over 2x FMA).
// Weights 192 floats/thread + ~40 working < 256 combined budget at
// 2 waves/SIMD; gfx950 VALU reads AGPR sources directly (proven by v5's
// VGPR_Count=64 at full speed), so the AGPR half holds the overflow.
// Fold = v5's all-DPP {7,2,1} tree, run once per unit. Single barrier,
// double-buffered z, branchless activations, quad-local c/h update.

#define T_STEPS 1024
#define ISZ 64
#define HSZ 128
#define ZSZ (ISZ + HSZ)   // concat operand per row: [x_t | h_{t-1}]
#define BCHUNK 2
#define NTH 512
#define CLEN 24           // K-chunk length per thread (192/8)
#define NU 2              // hidden units per thread-group

#define DPP_X1 0xB1       // quad_perm [1,0,3,2]  : lane ^= 1
#define DPP_X2 0x4E       // quad_perm [2,3,0,1]  : lane ^= 2
#define DPP_HM 0x141      // half_mirror          : lane ^= 7 (within 8-lane half)

template<int CTRL>
__device__ __forceinline__ float dppf(float v) {
    return __int_as_float(__builtin_amdgcn_mov_dpp(__float_as_int(v), CTRL, 0xF, 0xF, true));
}

__global__ __launch_bounds__(NTH, 2)  // 8 waves/block = 2 waves/EU -> 256-reg combined budget
void lstm_fused_kernel(const float* __restrict__ x,
                       const float* __restrict__ W_ih,
                       const float* __restrict__ W_hh,
                       const float* __restrict__ b_ih,
                       const float* __restrict__ b_hh,
                       const float* __restrict__ W1,
                       const float* __restrict__ b1,
                       const float* __restrict__ W2,
                       const float* __restrict__ b2,
                       float* __restrict__ out)
{
    // double-buffered [x_t(64) | h(128)] per row; step t reads one buffer,
    // writes h(t) and x(t+1) into the other. One barrier per step.
    __shared__ __align__(16) float zbuf[2][BCHUNK][ZSZ];
    __shared__ float red[BCHUNK][4];

    const int tid = threadIdx.x;
    const int b0 = blockIdx.x * BCHUNK;
    const int c   = tid & 7;     // chunk lane (0..7)
    const int grp = tid >> 3;    // unit group 0..63 (units 2grp, 2grp+1)
    const int cls = c & 3;       // gate class this lane owns after fold
    const int row = c >> 2;      // batch row this lane owns after fold

    // basis coordinates of lane c in {7,2,1}: c = alpha*7 ^ beta*2 ^ gamma*1
    const bool alpha = (c & 4) != 0;
    const int  c1r = c ^ (alpha ? 7 : 0);
    const bool beta  = (c1r & 2) != 0;
    const bool gamma = ((c1r ^ (beta ? 2 : 0)) & 1) != 0;
    const bool cls3  = (cls == 3);
    const bool cls13 = (cls & 1) != 0;

    // fused-activation constants: act = aa + bb * rcp(exp(kk*s) + 1)
    // cls 0,1,3 (sigmoid): kk=-1, aa=0, bb=1 ; cls 2 (tanh): kk=2, aa=1, bb=-2
    const float kk = (cls == 2) ?  2.0f : -1.0f;
    const float aa = (cls == 2) ?  1.0f :  0.0f;
    const float bb = (cls == 2) ? -2.0f :  1.0f;

    // ---- per-thread weights: 8 gate rows {cls*128 + 2grp + u}, cols [24c,24c+24) ----
    float wt[NU][4][CLEN];
    #pragma unroll
    for (int u = 0; u < NU; ++u)
        #pragma unroll
        for (int i = 0; i < 4; ++i) {
            const int g = i * HSZ + 2 * grp + u;
            const float* rih = W_ih + (size_t)g * ISZ;
            const float* rhh = W_hh + (size_t)g * HSZ;
            #pragma unroll
            for (int k = 0; k < CLEN; ++k) {
                const int col = c * CLEN + k;
                wt[u][i][k] = (col < ISZ) ? rih[col] : rhh[col - ISZ];
            }
        }
    float bias[NU];
    #pragma unroll
    for (int u = 0; u < NU; ++u) {
        const int g_own = cls * HSZ + 2 * grp + u;
        bias[u] = b_ih[g_own] + b_hh[g_own];
    }

    // ---- init buf0: h(-1)=0, x(0) ----
    if (tid < BCHUNK * HSZ) zbuf[0][tid >> 7][ISZ + (tid & 127)] = 0.0f;
    if (tid >= 256 && tid < 256 + BCHUNK * ISZ) {
        int l = tid - 256;
        zbuf[0][l >> 6][l & 63] =
            x[((size_t)(b0 + (l >> 6)) * T_STEPS + 0) * ISZ + (l & 63)];
    }
    float cst[NU] = {0.f, 0.f};  // c-state of (unit 2grp+u, row); quad-redundant, bit-consistent
    __syncthreads();

    auto step = [&](const float (*__restrict__ zr)[ZSZ],
                    float (*__restrict__ zw)[ZSZ], int t) {
        // x(t+1) prefetch issue (threads 256..383), stored to zw pre-barrier
        float xpre = 0.0f;
        const bool pf = (tid >= 256) && (tid < 384) && (t + 1 < T_STEPS);
        if (pf) {
            int l = tid - 256;
            xpre = x[((size_t)(b0 + (l >> 6)) * T_STEPS + (t + 1)) * ISZ + (l & 63)];
        }

        // ---- phase A: chunk partials for 2 units x 4 classes x 2 rows ----
        float a[NU][4][BCHUNK];
        #pragma unroll
        for (int u = 0; u < NU; ++u)
            #pragma unroll
            for (int i = 0; i < 4; ++i) { a[u][i][0] = 0.0f; a[u][i][1] = 0.0f; }
        #pragma unroll
        for (int r = 0; r < BCHUNK; ++r) {
            const float4* zp = reinterpret_cast<const float4*>(zr[r]) + c * (CLEN / 4);
            #pragma unroll
            for (int k = 0; k < CLEN / 4; ++k) {
                float4 U = zp[k];
                #pragma unroll
                for (int u = 0; u < NU; ++u)
                    #pragma unroll
                    for (int i = 0; i < 4; ++i) {
                        a[u][i][r] = fmaf(wt[u][i][4*k  ], U.x, a[u][i][r]);
                        a[u][i][r] = fmaf(wt[u][i][4*k+1], U.y, a[u][i][r]);
                        a[u][i][r] = fmaf(wt[u][i][4*k+2], U.z, a[u][i][r]);
                        a[u][i][r] = fmaf(wt[u][i][4*k+3], U.w, a[u][i][r]);
                    }
            }
        }

        // ---- all-DPP fold over 8 chunk lanes, basis {7,2,1}, once per unit ----
        // target lane for (cls,r): 4r+cls; v5-verified coord table.
        float S[NU];
        #pragma unroll
        for (int u = 0; u < NU; ++u) {
            float A000 = a[u][0][0], A001 = a[u][1][0], A010 = a[u][2][0], A011 = a[u][3][0];
            float A100 = a[u][3][1], A101 = a[u][2][1], A110 = a[u][1][1], A111 = a[u][0][1];
            float B00 = (alpha ? A100 : A000) + dppf<DPP_HM>(alpha ? A000 : A100);
            float B01 = (alpha ? A101 : A001) + dppf<DPP_HM>(alpha ? A001 : A101);
            float B10 = (alpha ? A110 : A010) + dppf<DPP_HM>(alpha ? A010 : A110);
            float B11 = (alpha ? A111 : A011) + dppf<DPP_HM>(alpha ? A011 : A111);
            float C0  = (beta ? B10 : B00) + dppf<DPP_X2>(beta ? B00 : B10);
            float C1  = (beta ? B11 : B01) + dppf<DPP_X2>(beta ? B01 : B11);
            S[u] = (gamma ? C1 : C0) + dppf<DPP_X1>(gamma ? C0 : C1) + bias[u];
        }

        // ---- activation + quad-local c/h update, per unit ----
        float hv[NU];
        #pragma unroll
        for (int u = 0; u < NU; ++u) {
            float e   = __expf(kk * S[u]);
            float act = fmaf(bb, __builtin_amdgcn_rcpf(e + 1.0f), aa);
            float prt = dppf<DPP_X2>(act);
            float m1  = act * prt;                 // classes 0,2: ig*gv (bitwise equal)
            float fgv = cls3 ? prt : act;          // classes 1,3: fg
            float x1v = cls13 ? fgv : m1;
            float rcv = dppf<DPP_X1>(x1v);         // swap with class^1
            float m1v = cls13 ? rcv : x1v;         // everyone: ig*gv
            float fgf = cls13 ? x1v : rcv;         // everyone: fg
            cst[u] = fmaf(fgf, cst[u], m1v);
            float e2 = __expf(2.0f * cst[u]);
            float th = fmaf(-2.0f, __builtin_amdgcn_rcpf(e2 + 1.0f), 1.0f);  // tanh
            hv[u] = act * th;                      // valid on cls3 lane (act = og)
        }
        if (cls3) {                                 // one writer per (unit-pair, row)
            float2 hw = { hv[0], hv[1] };
            *reinterpret_cast<float2*>(&zw[row][ISZ + 2 * grp]) = hw;
        }

        // x(t+1) store into next buffer (disjoint region from h writes)
        if (pf) {
            int l = tid - 256;
            zw[l >> 6][l & 63] = xpre;
        }
        __syncthreads();   // zw complete: h(t) + x(t+1)
    };

    for (int t = 0; t < T_STEPS; t += 2) {
        step(zbuf[0], zbuf[1], t);
        step(zbuf[1], zbuf[0], t + 1);
    }

    // ---- FC head: out[b] = W2 . (W1 h + b1) + b2 ----
    // last step t=1023 wrote h into zbuf[0]
    {
        const int b = tid >> 8;    // threads 0..255 -> row b0, 256..511 -> row b0+1
        const int m = tid & 255;
        const float4* w1r = reinterpret_cast<const float4*>(W1 + (size_t)m * HSZ);
        const float4* hr = reinterpret_cast<const float4*>(zbuf[0][b] + ISZ);
        float acc = 0.0f;
        #pragma unroll
        for (int k = 0; k < HSZ / 4; ++k) {
            float4 w = w1r[k];
            float4 h = hr[k];
            acc = fmaf(w.x, h.x, acc);
            acc = fmaf(w.y, h.y, acc);
            acc = fmaf(w.z, h.z, acc);
            acc = fmaf(w.w, h.w, acc);
        }
        float z = (acc + b1[m]) * W2[m];
        #pragma unroll
        for (int off = 32; off >= 1; off >>= 1)
            z += __shfl_down(z, off, 64);
        if ((tid & 63) == 0) red[b][(tid >> 6) & 3] = z;
    }
    __syncthreads();
    if (tid == 0)   out[b0]     = red[0][0] + red[0][1] + red[0][2] + red[0][3] + b2[0];
    if (tid == 256) out[b0 + 1] = red[1][0] + red[1][1] + red[1][2] + red[1][3] + b2[0];
}

extern "C" void kernel_launch(void* const* d_in, const int* in_sizes, int n_in,
                              void* d_out, int out_size, void* d_ws, size_t ws_size,
                              hipStream_t stream) {
    const float* x    = (const float*)d_in[0];
    const float* W_ih = (const float*)d_in[1];
    const float* W_hh = (const float*)d_in[2];
    const float* b_ih = (const float*)d_in[3];
    const float* b_hh = (const float*)d_in[4];
    const float* W1   = (const float*)d_in[5];
    const float* b1   = (const float*)d_in[6];
    const float* W2   = (const float*)d_in[7];
    const float* b2   = (const float*)d_in[8];
    float* out = (float*)d_out;

    lstm_fused_kernel<<<dim3(512 / BCHUNK), dim3(NTH), 0, stream>>>(
        x, W_ih, W_hh, b_ih, b_hh, W1, b1, W2, b2, out);
}